// Round 3
// baseline (109.834 us; speedup 1.0000x reference)
//
#include <hip/hip_runtime.h>

// ---------------------------------------------------------------------------
// cross_entropy_with_hnm_for_one_class_detection
//
// 3 scales: softmax-CE with hard-negative mining (k-th order statistic of
// neg_prob over N=B*H*W) + masked bbox MSE. Output: 3 floats.
//
// R2 bottleneck was LDS-atomic same-address serialization (bit-pattern bins
// concentrate). R3: LINEAR binning (uint)(v*4096) spreads near-uniformly;
// selected bin holds only ~hundreds of candidates -> exact 32-bit radix
// select over a tiny candidate list. cev array dropped (ce recomputed as
// -log(npv) in the final streaming pass).
// ---------------------------------------------------------------------------

namespace {
constexpr int BATCH = 32;
constexpr int HW0 = 25600, HW1 = 6400, HW2 = 1600;
constexpr int N0 = BATCH * HW0;  // 819200
constexpr int N1 = BATCH * HW1;  // 204800
constexpr int N2 = BATCH * HW2;  // 51200
constexpr int NT = N0 + N1 + N2;

constexpr int LBINS = 4096;
constexpr int CAP = 8192;  // candidate list capacity per scale

// one float4 per thread covers each scale in a single shot
constexpr int B0 = 832, B1 = 208, B2 = 52;  // 832*1024>=N0 etc.
constexpr int NBLK = B0 + B1 + B2;          // 1092

struct ScaleScal {
  unsigned int pos_cnt, neg_cnt;
  unsigned int sel_bin, sel_rank;
  unsigned int thr_bits, cand_cnt;
  unsigned int pad0, pad1;
  double sum_pos_ce, sum_diff2, sum_neg_ce, pad2;
};  // 64 bytes

__device__ inline void scale_of(int blk, int& s, int& rel, int& nb, int& N,
                                int& base) {
  if (blk < B0) {
    s = 0; rel = blk; nb = B0; N = N0; base = 0;
  } else if (blk < B0 + B1) {
    s = 1; rel = blk - B0; nb = B1; N = N1; base = N0;
  } else {
    s = 2; rel = blk - B0 - B1; nb = B2; N = N2; base = N0 + N1;
  }
}

__device__ inline unsigned int hnm_k(const ScaleScal& ss) {
  const unsigned long long k10 = 10ull * (unsigned long long)ss.pos_cnt;
  return (k10 < (unsigned long long)ss.neg_cnt) ? (unsigned int)k10
                                                : ss.neg_cnt;
}

__device__ inline unsigned int lin_bin(float v) {
  unsigned int b = (unsigned int)(v * 4096.0f);
  return b > 4095u ? 4095u : b;
}

// Block-wide: stage global hist (LBINS) into lds, find bin containing rank k.
// Results in *sel_bin / *sel_rank (caller-shared); valid after return.
__device__ void select_bin(const unsigned int* __restrict__ h, unsigned int k,
                           unsigned int* __restrict__ lds,
                           unsigned int* sel_bin, unsigned int* sel_rank) {
  const int tid = threadIdx.x;
  for (int i = tid; i < LBINS; i += 256) lds[i] = h[i];  // coalesced stage
  __syncthreads();
  __shared__ unsigned int part[256];
  constexpr int per = LBINS / 256;
  unsigned int own = 0;
#pragma unroll
  for (int i = 0; i < per; ++i) own += lds[tid * per + i];
  part[tid] = own;
  __syncthreads();
  for (int o = 1; o < 256; o <<= 1) {  // inclusive Hillis-Steele
    const unsigned int add = (tid >= o) ? part[tid - o] : 0u;
    __syncthreads();
    part[tid] += add;
    __syncthreads();
  }
  const unsigned int incl = part[tid];
  const unsigned int excl = incl - own;
  if (own && k >= excl && k < incl) {  // unique winner
    unsigned int run = excl;
#pragma unroll
    for (int i = 0; i < per; ++i) {
      const unsigned int c = lds[tid * per + i];
      if (run + c > k) {
        *sel_bin = (unsigned int)(tid * per + i);
        *sel_rank = k - run;
        break;
      }
      run += c;
    }
  }
  __syncthreads();
}
}  // namespace

// ---------------- pass 1: softmax, counts, pos-CE, bbox, linear hist --------
template <int HW, int N>
__device__ void pass1_body(int rel, const float* __restrict__ sc,
                           const float* __restrict__ bb,
                           const float* __restrict__ gl,
                           unsigned int* __restrict__ hist,
                           ScaleScal* __restrict__ ss,
                           float* __restrict__ npv,
                           unsigned int* __restrict__ lh) {
  const int tid = threadIdx.x;
  for (int i = tid; i < LBINS; i += 256) lh[i] = 0;
  __syncthreads();

  double posce = 0.0, diff2 = 0.0;
  unsigned int pcnt = 0, ncnt = 0;
  const int q = (rel * 256 + tid) * 4;
  if (q < N) {
    const int b = q / HW;
    const int hw = q - b * HW;
    const float4 s0v = *(const float4*)(sc + (size_t)b * 2 * HW + hw);
    const float4 s1v = *(const float4*)(sc + (size_t)b * 2 * HW + HW + hw);
    const float4 l0v = *(const float4*)(gl + (size_t)b * 6 * HW + hw);
    const float4 l1v = *(const float4*)(gl + (size_t)b * 6 * HW + HW + hw);
    const float s0a[4] = {s0v.x, s0v.y, s0v.z, s0v.w};
    const float s1a[4] = {s1v.x, s1v.y, s1v.z, s1v.w};
    const float l0a[4] = {l0v.x, l0v.y, l0v.z, l0v.w};
    const float l1a[4] = {l1v.x, l1v.y, l1v.z, l1v.w};
    float np[4];
#pragma unroll
    for (int j = 0; j < 4; ++j) {
      const float d = s1a[j] - s0a[j];
      const float t = expf(-fabsf(d));
      const float l1p = log1pf(t);  // = lse after max-sub
      const bool pos = l0a[j] > 0.5f;
      const bool neg = l1a[j] > 0.5f;
      const float sm1 = ((d >= 0.0f) ? 1.0f : t) / (1.0f + t);
      const float v = neg ? sm1 : 0.0f;
      np[j] = v;
      atomicAdd(&lh[lin_bin(v)], 1u);
      if (neg) ncnt++;
      if (pos) {
        pcnt++;
        const float ls0 = ((d > 0.0f) ? -d : 0.0f) - l1p;
        posce += (double)(-l0a[j] * ls0);
        const float* glp = gl + (size_t)b * 6 * HW + hw + j;
        const float* bbp = bb + (size_t)b * 4 * HW + hw + j;
        float acc = 0.0f;
#pragma unroll
        for (int c = 0; c < 4; ++c) {
          const float dd = glp[(2 + c) * HW] - bbp[c * HW];
          acc += dd * dd;
        }
        diff2 += (double)acc;
      }
    }
    *(float4*)(npv + q) = make_float4(np[0], np[1], np[2], np[3]);
  }
  __syncthreads();
  for (int i = tid; i < LBINS; i += 256) {
    const unsigned int c = lh[i];
    if (c) atomicAdd(&hist[i], c);
  }

  __shared__ double sd[256];
  __shared__ unsigned int su[256];
  sd[tid] = posce;
  su[tid] = pcnt;
  __syncthreads();
  for (int o = 128; o > 0; o >>= 1) {
    if (tid < o) { sd[tid] += sd[tid + o]; su[tid] += su[tid + o]; }
    __syncthreads();
  }
  if (tid == 0) {
    if (sd[0] != 0.0) atomicAdd(&ss->sum_pos_ce, sd[0]);
    if (su[0]) atomicAdd(&ss->pos_cnt, su[0]);
  }
  __syncthreads();
  sd[tid] = diff2;
  su[tid] = ncnt;
  __syncthreads();
  for (int o = 128; o > 0; o >>= 1) {
    if (tid < o) { sd[tid] += sd[tid + o]; su[tid] += su[tid + o]; }
    __syncthreads();
  }
  if (tid == 0) {
    if (sd[0] != 0.0) atomicAdd(&ss->sum_diff2, sd[0]);
    if (su[0]) atomicAdd(&ss->neg_cnt, su[0]);
  }
}

__global__ __launch_bounds__(256) void k_pass1(
    const float* sc0, const float* bb0, const float* gl0,
    const float* sc1, const float* bb1, const float* gl1,
    const float* sc2, const float* bb2, const float* gl2,
    unsigned int* hist, ScaleScal* scal, float* npv) {
  __shared__ unsigned int lh[LBINS];
  int s, rel, nb, N, base;
  scale_of(blockIdx.x, s, rel, nb, N, base);
  if (s == 0)
    pass1_body<HW0, N0>(rel, sc0, bb0, gl0, hist, scal, npv, lh);
  else if (s == 1)
    pass1_body<HW1, N1>(rel, sc1, bb1, gl1, hist + LBINS, scal + 1, npv + N0, lh);
  else
    pass1_body<HW2, N2>(rel, sc2, bb2, gl2, hist + 2 * LBINS, scal + 2,
                        npv + N0 + N1, lh);
}

// ---------------- pass 2: gather candidates of selected linear bin ----------
__global__ __launch_bounds__(256) void k_cand(
    const unsigned int* __restrict__ hist, const float* __restrict__ npv,
    ScaleScal* scal, unsigned int* __restrict__ cand) {
  __shared__ unsigned int lds[LBINS];
  __shared__ unsigned int selb, selr;
  int s, rel, nb, N, base;
  scale_of(blockIdx.x, s, rel, nb, N, base);
  select_bin(hist + s * LBINS, hnm_k(scal[s]), lds, &selb, &selr);
  if (rel == 0 && threadIdx.x == 0) {
    scal[s].sel_bin = selb;
    scal[s].sel_rank = selr;
  }
  const unsigned int b = selb;
  unsigned int* lst = cand + s * CAP;
  const int q = (rel * 256 + threadIdx.x) * 4;
  if (q < N) {
    const float4 v4 = *(const float4*)(npv + base + q);
    const float va[4] = {v4.x, v4.y, v4.z, v4.w};
#pragma unroll
    for (int j = 0; j < 4; ++j) {
      if (lin_bin(va[j]) == b) {
        const unsigned int slot = atomicAdd(&scal[s].cand_cnt, 1u);
        if (slot < CAP) lst[slot] = __float_as_uint(va[j]);
      }
    }
  }
}

// ---------------- pass 3: exact radix select over candidate list ------------
__global__ __launch_bounds__(256) void k_select(ScaleScal* scal,
                                                const unsigned int* __restrict__ cand) {
  const int s = blockIdx.x;
  const int tid = threadIdx.x;
  __shared__ unsigned int vals[CAP];  // 32 KiB
  __shared__ unsigned int hist[256];
  __shared__ unsigned int sh_prefix, sh_rank, sh_sel;
  const unsigned int n = min(scal[s].cand_cnt, (unsigned int)CAP);
  if (tid == 0) {
    sh_prefix = 0;
    sh_rank = scal[s].sel_rank;
  }
  for (unsigned int i = tid; i < n; i += 256) vals[i] = cand[s * CAP + i];
  __syncthreads();
#pragma unroll
  for (int round = 0; round < 4; ++round) {
    const int shift = 24 - 8 * round;
    hist[tid] = 0;
    __syncthreads();
    const unsigned int pref = sh_prefix;
    for (unsigned int i = tid; i < n; i += 256) {
      const unsigned int v = vals[i];
      const bool match =
          (round == 0) || ((v >> (shift + 8)) == (pref >> (shift + 8)));
      if (match) atomicAdd(&hist[(v >> shift) & 255u], 1u);
    }
    __syncthreads();
    if (tid == 0) {
      unsigned int k = sh_rank, run = 0, sel = 255;
      for (int bkt = 0; bkt < 256; ++bkt) {
        const unsigned int c = hist[bkt];
        if (run + c > k) { sel = (unsigned int)bkt; break; }
        run += c;
      }
      sh_prefix = pref | (sel << shift);
      sh_rank = k - run;
    }
    __syncthreads();
  }
  if (tid == 0) scal[s].thr_bits = sh_prefix;
}

// ---------------- pass 4: sum CE of selected negatives ----------------------
__global__ __launch_bounds__(256) void k_negce(const float* __restrict__ npv,
                                               ScaleScal* scal) {
  int s, rel, nb, N, base;
  scale_of(blockIdx.x, s, rel, nb, N, base);
  const float thr = __uint_as_float(scal[s].thr_bits);
  double acc = 0.0;
  const int tid = threadIdx.x;
  const int q = (rel * 256 + tid) * 4;
  if (q < N) {
    const float4 v4 = *(const float4*)(npv + base + q);
    const float va[4] = {v4.x, v4.y, v4.z, v4.w};
#pragma unroll
    for (int j = 0; j < 4; ++j) {
      const float v = va[j];
      if (v > 0.0f && v <= thr) acc += (double)(-logf(v));
    }
  }
  __shared__ double sd[256];
  sd[tid] = acc;
  __syncthreads();
  for (int o = 128; o > 0; o >>= 1) {
    if (tid < o) sd[tid] += sd[tid + o];
    __syncthreads();
  }
  if (tid == 0 && sd[0] != 0.0) atomicAdd(&scal[s].sum_neg_ce, sd[0]);
}

// ---------------- pass 5: finalize ------------------------------------------
__global__ void k_final(const ScaleScal* __restrict__ scal,
                        float* __restrict__ out) {
  const int s = threadIdx.x;
  if (s < 3) {
    const ScaleScal& ss = scal[s];
    const double Ns = (s == 0) ? (double)N0 : (s == 1) ? (double)N1 : (double)N2;
    const double W = (s == 0) ? 160.0 : (s == 1) ? 80.0 : 40.0;
    const double ls = (ss.sum_pos_ce + ss.sum_neg_ce) / (2.0 * Ns);
    const double lb = (ss.sum_diff2 / W) / (4.0 * (double)ss.pos_cnt);
    out[s] = (float)(ls + lb);
  }
}

extern "C" void kernel_launch(void* const* d_in, const int* in_sizes, int n_in,
                              void* d_out, int out_size, void* d_ws,
                              size_t ws_size, hipStream_t stream) {
  const float* sc0 = (const float*)d_in[0];
  const float* bb0 = (const float*)d_in[1];
  const float* gl0 = (const float*)d_in[3];
  const float* sc1 = (const float*)d_in[4];
  const float* bb1 = (const float*)d_in[5];
  const float* gl1 = (const float*)d_in[7];
  const float* sc2 = (const float*)d_in[8];
  const float* bb2 = (const float*)d_in[9];
  const float* gl2 = (const float*)d_in[11];

  char* ws = (char*)d_ws;
  unsigned int* hist = (unsigned int*)ws;                 // 3*4096 u32
  ScaleScal* scal = (ScaleScal*)(hist + 3 * LBINS);       // 3 structs
  size_t zbytes = (size_t)3 * LBINS * 4 + 3 * sizeof(ScaleScal);
  zbytes = (zbytes + 255) & ~(size_t)255;
  unsigned int* cand = (unsigned int*)(ws + zbytes);      // 3*CAP u32
  size_t cbytes = (zbytes + (size_t)3 * CAP * 4 + 255) & ~(size_t)255;
  float* npv = (float*)(ws + cbytes);                     // NT floats

  hipMemsetAsync(d_ws, 0, zbytes, stream);  // hist + scal only

  const dim3 blk(256);
  const dim3 grd(NBLK);
  k_pass1<<<grd, blk, 0, stream>>>(sc0, bb0, gl0, sc1, bb1, gl1, sc2, bb2, gl2,
                                   hist, scal, npv);
  k_cand<<<grd, blk, 0, stream>>>(hist, npv, scal, cand);
  k_select<<<dim3(3), blk, 0, stream>>>(scal, cand);
  k_negce<<<grd, blk, 0, stream>>>(npv, scal);
  k_final<<<1, 64, 0, stream>>>(scal, (float*)d_out);
}

// Round 4
// 82.673 us; speedup vs baseline: 1.3285x; 1.3285x over previous
//
#include <hip/hip_runtime.h>

// ---------------------------------------------------------------------------
// cross_entropy_with_hnm_for_one_class_detection
//
// 3 scales: softmax-CE with hard-negative mining (k-th order statistic of
// neg_prob over N=B*H*W) + masked bbox MSE. Output: 3 floats.
//
// R3 bottleneck: atomicAdd(double) == CAS retry loop, 1092 contenders on the
// same 4 addresses (and again in k_negce). R4: NO f64 atomics anywhere --
// per-block partial slots + tiny reduce kernels. u32 histogram atomics
// (hardware, fire-and-forget) remain.
// ---------------------------------------------------------------------------

namespace {
constexpr int BATCH = 32;
constexpr int HW0 = 25600, HW1 = 6400, HW2 = 1600;
constexpr int N0 = BATCH * HW0;  // 819200
constexpr int N1 = BATCH * HW1;  // 204800
constexpr int N2 = BATCH * HW2;  // 51200
constexpr int NT = N0 + N1 + N2;

constexpr int LBINS = 4096;
constexpr int CAP = 8192;  // candidate list capacity per scale

// one float4 per thread covers each scale in a single shot
constexpr int B0 = 832, B1 = 208, B2 = 52;
constexpr int NBLK = B0 + B1 + B2;  // 1092

struct ScaleScal {
  unsigned int pos_cnt, neg_cnt;
  unsigned int sel_bin, sel_rank;
  unsigned int thr_bits, cand_cnt;
  unsigned int pad0, pad1;
  double sum_pos_ce, sum_diff2;
};  // 48 bytes

struct P1 {
  double posce, diff2;
  unsigned int pcnt, ncnt;
  unsigned long long pad;
};  // 32 bytes

__device__ inline void scale_of(int blk, int& s, int& rel, int& nb, int& N,
                                int& base) {
  if (blk < B0) {
    s = 0; rel = blk; nb = B0; N = N0; base = 0;
  } else if (blk < B0 + B1) {
    s = 1; rel = blk - B0; nb = B1; N = N1; base = N0;
  } else {
    s = 2; rel = blk - B0 - B1; nb = B2; N = N2; base = N0 + N1;
  }
}

__device__ inline unsigned int lin_bin(float v) {
  unsigned int b = (unsigned int)(v * 4096.0f);
  return b > 4095u ? 4095u : b;
}

// Block-wide: stage global hist into lds, find bin containing rank k.
__device__ void select_bin(const unsigned int* __restrict__ h, unsigned int k,
                           unsigned int* __restrict__ lds,
                           unsigned int* sel_bin, unsigned int* sel_rank) {
  const int tid = threadIdx.x;
  for (int i = tid; i < LBINS; i += 256) lds[i] = h[i];
  __syncthreads();
  __shared__ unsigned int part[256];
  constexpr int per = LBINS / 256;
  unsigned int own = 0;
#pragma unroll
  for (int i = 0; i < per; ++i) own += lds[tid * per + i];
  part[tid] = own;
  __syncthreads();
  for (int o = 1; o < 256; o <<= 1) {  // inclusive Hillis-Steele
    const unsigned int add = (tid >= o) ? part[tid - o] : 0u;
    __syncthreads();
    part[tid] += add;
    __syncthreads();
  }
  const unsigned int incl = part[tid];
  const unsigned int excl = incl - own;
  if (own && k >= excl && k < incl) {  // unique winner
    unsigned int run = excl;
#pragma unroll
    for (int i = 0; i < per; ++i) {
      const unsigned int c = lds[tid * per + i];
      if (run + c > k) {
        *sel_bin = (unsigned int)(tid * per + i);
        *sel_rank = k - run;
        break;
      }
      run += c;
    }
  }
  __syncthreads();
}
}  // namespace

// ---------------- pass 1: softmax, counts, pos-CE, bbox, linear hist --------
template <int HW, int N>
__device__ void pass1_body(int rel, const float* __restrict__ sc,
                           const float* __restrict__ bb,
                           const float* __restrict__ gl,
                           unsigned int* __restrict__ hist,
                           float* __restrict__ npv,
                           unsigned int* __restrict__ lh, P1* __restrict__ p1) {
  const int tid = threadIdx.x;
  for (int i = tid; i < LBINS; i += 256) lh[i] = 0;
  __syncthreads();

  double posce = 0.0, diff2 = 0.0;
  unsigned int pcnt = 0, ncnt = 0;
  const int q = (rel * 256 + tid) * 4;
  if (q < N) {
    const int b = q / HW;
    const int hw = q - b * HW;
    const float4 s0v = *(const float4*)(sc + (size_t)b * 2 * HW + hw);
    const float4 s1v = *(const float4*)(sc + (size_t)b * 2 * HW + HW + hw);
    const float4 l0v = *(const float4*)(gl + (size_t)b * 6 * HW + hw);
    const float4 l1v = *(const float4*)(gl + (size_t)b * 6 * HW + HW + hw);
    const float s0a[4] = {s0v.x, s0v.y, s0v.z, s0v.w};
    const float s1a[4] = {s1v.x, s1v.y, s1v.z, s1v.w};
    const float l0a[4] = {l0v.x, l0v.y, l0v.z, l0v.w};
    const float l1a[4] = {l1v.x, l1v.y, l1v.z, l1v.w};
    float np[4];
#pragma unroll
    for (int j = 0; j < 4; ++j) {
      const float d = s1a[j] - s0a[j];
      const float t = expf(-fabsf(d));
      const float l1p = log1pf(t);  // = lse after max-sub
      const bool pos = l0a[j] > 0.5f;
      const bool neg = l1a[j] > 0.5f;
      const float sm1 = ((d >= 0.0f) ? 1.0f : t) / (1.0f + t);
      const float v = neg ? sm1 : 0.0f;
      np[j] = v;
      atomicAdd(&lh[lin_bin(v)], 1u);
      if (neg) ncnt++;
      if (pos) {
        pcnt++;
        const float ls0 = ((d > 0.0f) ? -d : 0.0f) - l1p;
        posce += (double)(-l0a[j] * ls0);
        const float* glp = gl + (size_t)b * 6 * HW + hw + j;
        const float* bbp = bb + (size_t)b * 4 * HW + hw + j;
        float acc = 0.0f;
#pragma unroll
        for (int c = 0; c < 4; ++c) {
          const float dd = glp[(2 + c) * HW] - bbp[c * HW];
          acc += dd * dd;
        }
        diff2 += (double)acc;
      }
    }
    *(float4*)(npv + q) = make_float4(np[0], np[1], np[2], np[3]);
  }
  __syncthreads();
  for (int i = tid; i < LBINS; i += 256) {
    const unsigned int c = lh[i];
    if (c) atomicAdd(&hist[i], c);  // u32 HW atomic, fire-and-forget
  }

  __shared__ double sd[256];
  __shared__ unsigned int su[256];
  sd[tid] = posce;
  su[tid] = pcnt;
  __syncthreads();
  for (int o = 128; o > 0; o >>= 1) {
    if (tid < o) { sd[tid] += sd[tid + o]; su[tid] += su[tid + o]; }
    __syncthreads();
  }
  if (tid == 0) { p1->posce = sd[0]; p1->pcnt = su[0]; }
  __syncthreads();
  sd[tid] = diff2;
  su[tid] = ncnt;
  __syncthreads();
  for (int o = 128; o > 0; o >>= 1) {
    if (tid < o) { sd[tid] += sd[tid + o]; su[tid] += su[tid + o]; }
    __syncthreads();
  }
  if (tid == 0) { p1->diff2 = sd[0]; p1->ncnt = su[0]; }
}

__global__ __launch_bounds__(256) void k_pass1(
    const float* sc0, const float* bb0, const float* gl0,
    const float* sc1, const float* bb1, const float* gl1,
    const float* sc2, const float* bb2, const float* gl2,
    unsigned int* hist, float* npv, P1* part1) {
  __shared__ unsigned int lh[LBINS];
  int s, rel, nb, N, base;
  scale_of(blockIdx.x, s, rel, nb, N, base);
  P1* p1 = part1 + blockIdx.x;
  if (s == 0)
    pass1_body<HW0, N0>(rel, sc0, bb0, gl0, hist, npv, lh, p1);
  else if (s == 1)
    pass1_body<HW1, N1>(rel, sc1, bb1, gl1, hist + LBINS, npv + N0, lh, p1);
  else
    pass1_body<HW2, N2>(rel, sc2, bb2, gl2, hist + 2 * LBINS, npv + N0 + N1,
                        lh, p1);
}

// ---------------- pass 2: reduce partials, compute k, scan hist once --------
__global__ __launch_bounds__(256) void k_mid(const P1* __restrict__ part1,
                                             const unsigned int* __restrict__ hist,
                                             ScaleScal* scal) {
  const int s = blockIdx.x;
  const int lo = (s == 0) ? 0 : (s == 1) ? B0 : B0 + B1;
  const int hi = (s == 0) ? B0 : (s == 1) ? B0 + B1 : NBLK;
  const int tid = threadIdx.x;
  __shared__ double sda[256], sdb[256];
  __shared__ unsigned int sua[256], sub[256];
  double a = 0, b = 0;
  unsigned int c = 0, d = 0;
  for (int i = lo + tid; i < hi; i += 256) {
    a += part1[i].posce; b += part1[i].diff2;
    c += part1[i].pcnt;  d += part1[i].ncnt;
  }
  sda[tid] = a; sdb[tid] = b; sua[tid] = c; sub[tid] = d;
  __syncthreads();
  for (int o = 128; o > 0; o >>= 1) {
    if (tid < o) {
      sda[tid] += sda[tid + o]; sdb[tid] += sdb[tid + o];
      sua[tid] += sua[tid + o]; sub[tid] += sub[tid + o];
    }
    __syncthreads();
  }
  __shared__ unsigned int kk;
  if (tid == 0) {
    scal[s].sum_pos_ce = sda[0];
    scal[s].sum_diff2 = sdb[0];
    scal[s].pos_cnt = sua[0];
    scal[s].neg_cnt = sub[0];
    const unsigned long long k10 = 10ull * (unsigned long long)sua[0];
    kk = (k10 < (unsigned long long)sub[0]) ? (unsigned int)k10 : sub[0];
  }
  __syncthreads();
  __shared__ unsigned int lds[LBINS];
  __shared__ unsigned int selb, selr;
  select_bin(hist + s * LBINS, kk, lds, &selb, &selr);
  if (tid == 0) { scal[s].sel_bin = selb; scal[s].sel_rank = selr; }
}

// ---------------- pass 3: gather candidates of selected linear bin ----------
__global__ __launch_bounds__(256) void k_cand(const float* __restrict__ npv,
                                              ScaleScal* scal,
                                              unsigned int* __restrict__ cand) {
  int s, rel, nb, N, base;
  scale_of(blockIdx.x, s, rel, nb, N, base);
  const unsigned int bsel = scal[s].sel_bin;
  unsigned int* lst = cand + s * CAP;
  const int q = (rel * 256 + threadIdx.x) * 4;
  if (q < N) {
    const float4 v4 = *(const float4*)(npv + base + q);
    const float va[4] = {v4.x, v4.y, v4.z, v4.w};
#pragma unroll
    for (int j = 0; j < 4; ++j) {
      if (lin_bin(va[j]) == bsel) {
        const unsigned int slot = atomicAdd(&scal[s].cand_cnt, 1u);
        if (slot < CAP) lst[slot] = __float_as_uint(va[j]);
      }
    }
  }
}

// ---------------- pass 4: exact radix select over candidate list ------------
__global__ __launch_bounds__(256) void k_select(
    ScaleScal* scal, const unsigned int* __restrict__ cand) {
  const int s = blockIdx.x;
  const int tid = threadIdx.x;
  __shared__ unsigned int vals[CAP];  // 32 KiB
  __shared__ unsigned int hist[256];
  __shared__ unsigned int sh_prefix, sh_rank;
  const unsigned int n = min(scal[s].cand_cnt, (unsigned int)CAP);
  if (tid == 0) {
    sh_prefix = 0;
    sh_rank = scal[s].sel_rank;
  }
  for (unsigned int i = tid; i < n; i += 256) vals[i] = cand[s * CAP + i];
  __syncthreads();
#pragma unroll
  for (int round = 0; round < 4; ++round) {
    const int shift = 24 - 8 * round;
    hist[tid] = 0;
    __syncthreads();
    const unsigned int pref = sh_prefix;
    for (unsigned int i = tid; i < n; i += 256) {
      const unsigned int v = vals[i];
      const bool match =
          (round == 0) || ((v >> (shift + 8)) == (pref >> (shift + 8)));
      if (match) atomicAdd(&hist[(v >> shift) & 255u], 1u);
    }
    __syncthreads();
    if (tid == 0) {
      unsigned int k = sh_rank, run = 0, sel = 255;
      for (int bkt = 0; bkt < 256; ++bkt) {
        const unsigned int c = hist[bkt];
        if (run + c > k) { sel = (unsigned int)bkt; break; }
        run += c;
      }
      sh_prefix = pref | (sel << shift);
      sh_rank = k - run;
    }
    __syncthreads();
  }
  if (tid == 0) scal[s].thr_bits = sh_prefix;
}

// ---------------- pass 5: sum CE of selected negatives (partials) -----------
__global__ __launch_bounds__(256) void k_negce(const float* __restrict__ npv,
                                               const ScaleScal* __restrict__ scal,
                                               double* __restrict__ part2) {
  int s, rel, nb, N, base;
  scale_of(blockIdx.x, s, rel, nb, N, base);
  const float thr = __uint_as_float(scal[s].thr_bits);
  double acc = 0.0;
  const int tid = threadIdx.x;
  const int q = (rel * 256 + tid) * 4;
  if (q < N) {
    const float4 v4 = *(const float4*)(npv + base + q);
    const float va[4] = {v4.x, v4.y, v4.z, v4.w};
#pragma unroll
    for (int j = 0; j < 4; ++j) {
      const float v = va[j];
      if (v > 0.0f && v <= thr) acc += (double)(-logf(v));
    }
  }
  __shared__ double sd[256];
  sd[tid] = acc;
  __syncthreads();
  for (int o = 128; o > 0; o >>= 1) {
    if (tid < o) sd[tid] += sd[tid + o];
    __syncthreads();
  }
  if (tid == 0) part2[blockIdx.x] = sd[0];
}

// ---------------- pass 6: finalize ------------------------------------------
__global__ __launch_bounds__(256) void k_final(const ScaleScal* __restrict__ scal,
                                               const double* __restrict__ part2,
                                               float* __restrict__ out) {
  const int tid = threadIdx.x;
  __shared__ double sd[256];
  for (int s = 0; s < 3; ++s) {
    const int lo = (s == 0) ? 0 : (s == 1) ? B0 : B0 + B1;
    const int hi = (s == 0) ? B0 : (s == 1) ? B0 + B1 : NBLK;
    double a = 0;
    for (int i = lo + tid; i < hi; i += 256) a += part2[i];
    sd[tid] = a;
    __syncthreads();
    for (int o = 128; o > 0; o >>= 1) {
      if (tid < o) sd[tid] += sd[tid + o];
      __syncthreads();
    }
    if (tid == 0) {
      const ScaleScal& ss = scal[s];
      const double Ns = (s == 0) ? (double)N0 : (s == 1) ? (double)N1 : (double)N2;
      const double W = (s == 0) ? 160.0 : (s == 1) ? 80.0 : 40.0;
      const double ls = (ss.sum_pos_ce + sd[0]) / (2.0 * Ns);
      const double lb = (ss.sum_diff2 / W) / (4.0 * (double)ss.pos_cnt);
      out[s] = (float)(ls + lb);
    }
    __syncthreads();
  }
}

extern "C" void kernel_launch(void* const* d_in, const int* in_sizes, int n_in,
                              void* d_out, int out_size, void* d_ws,
                              size_t ws_size, hipStream_t stream) {
  const float* sc0 = (const float*)d_in[0];
  const float* bb0 = (const float*)d_in[1];
  const float* gl0 = (const float*)d_in[3];
  const float* sc1 = (const float*)d_in[4];
  const float* bb1 = (const float*)d_in[5];
  const float* gl1 = (const float*)d_in[7];
  const float* sc2 = (const float*)d_in[8];
  const float* bb2 = (const float*)d_in[9];
  const float* gl2 = (const float*)d_in[11];

  char* ws = (char*)d_ws;
  unsigned int* hist = (unsigned int*)ws;            // 3*4096 u32 = 48 KiB
  ScaleScal* scal = (ScaleScal*)(hist + 3 * LBINS);  // 3 * 48 B
  size_t zbytes = (size_t)3 * LBINS * 4 + 3 * sizeof(ScaleScal);
  zbytes = (zbytes + 255) & ~(size_t)255;
  P1* part1 = (P1*)(ws + zbytes);                    // NBLK * 32 B
  size_t off = zbytes + (size_t)NBLK * sizeof(P1);
  off = (off + 255) & ~(size_t)255;
  double* part2 = (double*)(ws + off);               // NBLK * 8 B
  off += (size_t)NBLK * 8;
  off = (off + 255) & ~(size_t)255;
  unsigned int* cand = (unsigned int*)(ws + off);    // 3*CAP u32
  off += (size_t)3 * CAP * 4;
  off = (off + 255) & ~(size_t)255;
  float* npv = (float*)(ws + off);                   // NT floats

  hipMemsetAsync(d_ws, 0, zbytes, stream);  // hist + scal only

  const dim3 blk(256);
  const dim3 grd(NBLK);
  k_pass1<<<grd, blk, 0, stream>>>(sc0, bb0, gl0, sc1, bb1, gl1, sc2, bb2, gl2,
                                   hist, npv, part1);
  k_mid<<<dim3(3), blk, 0, stream>>>(part1, hist, scal);
  k_cand<<<grd, blk, 0, stream>>>(npv, scal, cand);
  k_select<<<dim3(3), blk, 0, stream>>>(scal, cand);
  k_negce<<<grd, blk, 0, stream>>>(npv, scal, part2);
  k_final<<<1, blk, 0, stream>>>(scal, part2, (float*)d_out);
}